// Round 2
// baseline (2704.733 us; speedup 1.0000x reference)
//
#include <hip/hip_runtime.h>

#define BATCH    1048576
#define IN_DIM   16
#define ODE_DIM  64
#define OUT_DIM  16
#define N_STEPS  32

typedef _Float16 half2v __attribute__((ext_vector_type(2)));
typedef _Float16 half4v __attribute__((ext_vector_type(4)));
typedef _Float16 half8v __attribute__((ext_vector_type(8)));
typedef float    f32x16 __attribute__((ext_vector_type(16)));

// 64 dims + 4 pad halfs per row: keeps 8B alignment for b64 DS ops and
// limits bank aliasing to 2-way (free, m136).
#define ROWSTRIDE 68

__device__ __forceinline__ float fast_tanh(float x) {
    // tanh(x) = 1 - 2/(exp2(2*log2e*x) + 1); robust at +/-inf (exp2->inf => 1, exp2->0 => -1)
    float e = __builtin_amdgcn_exp2f(x * 2.88539008177792681f);
    float r = __builtin_amdgcn_rcpf(e + 1.0f);
    return __builtin_fmaf(-2.0f, r, 1.0f);
}

__device__ __forceinline__ half2v pack_f16(float a, float b) {
    return __builtin_bit_cast(half2v, __builtin_amdgcn_cvt_pkrtz(a, b));
}

// State layout per wave (transposed): Y^T[dim=64][batch=32].
// Stored as two 32x32 MFMA C-frags (f32x16 each):
//   value (t, reg) at lane (h=lane>>5, b=lane&31):
//     dim   = 32*t + (reg&3) + 8*(reg>>2) + 4*h
//     batch = b
// f-eval: K^T = tanh(Wf^T @ tmp^T + bf) via 2 M-tiles x 4 K-tiles of
// v_mfma_f32_32x32x16_f16, A = Wf^T constant in registers.
__global__ __launch_bounds__(256) void ode_rk4_kernel(
    const float* __restrict__ x,
    const float* __restrict__ W_in,  const float* __restrict__ b_in,
    const float* __restrict__ Wf,    const float* __restrict__ bf,
    const float* __restrict__ W_out, const float* __restrict__ b_out,
    float* __restrict__ out)
{
    __shared__ _Float16 lds[4 * 32 * ROWSTRIDE];

    const int tid  = threadIdx.x;
    const int wv   = tid >> 6;
    const int lane = tid & 63;
    const int b    = lane & 31;   // batch column owned by this lane
    const int h    = lane >> 5;   // half-wave index
    _Float16* rowp = &lds[(wv * 32 + b) * ROWSTRIDE];

    const int batch0 = (blockIdx.x * 4 + wv) * 32;

    // ---- constant fragments: A = Wf^T, A[m][k] = Wf[k][m], m=32t+b, k=16q+8h+j ----
    half8v a_wf0[4], a_wf1[4];
    #pragma unroll
    for (int q = 0; q < 4; ++q) {
        #pragma unroll
        for (int j = 0; j < 8; ++j) {
            int k = 16 * q + 8 * h + j;
            a_wf0[q][j] = (_Float16)Wf[k * 64 + b];
            a_wf1[q][j] = (_Float16)Wf[k * 64 + 32 + b];
        }
    }
    // bias bf in C-layout (used as MFMA C-init each eval: free bias add)
    f32x16 bias0, bias1;
    #pragma unroll
    for (int r = 0; r < 16; ++r) {
        int row = (r & 3) + 8 * (r >> 2) + 4 * h;
        bias0[r] = bf[row];
        bias1[r] = bf[32 + row];
    }

    // ---- input layer: Y0^T = W_in^T @ x^T + b_in (single K-tile, K=16) ----
    f32x16 y0v, y1v;
    {
        const float* xp = x + (batch0 + b) * IN_DIM + 8 * h;
        float4 xa = *(const float4*)xp;
        float4 xc = *(const float4*)(xp + 4);
        half2v q0 = pack_f16(xa.x, xa.y);
        half2v q1 = pack_f16(xa.z, xa.w);
        half2v q2 = pack_f16(xc.x, xc.y);
        half2v q3 = pack_f16(xc.z, xc.w);
        half4v lo = __builtin_shufflevector(q0, q1, 0, 1, 2, 3);
        half4v hi = __builtin_shufflevector(q2, q3, 0, 1, 2, 3);
        half8v bx = __builtin_shufflevector(lo, hi, 0, 1, 2, 3, 4, 5, 6, 7);

        half8v a0, a1;
        #pragma unroll
        for (int j = 0; j < 8; ++j) {
            int k = 8 * h + j;                 // k in [0,16)
            a0[j] = (_Float16)W_in[k * 64 + b];
            a1[j] = (_Float16)W_in[k * 64 + 32 + b];
        }
        f32x16 c0, c1;
        #pragma unroll
        for (int r = 0; r < 16; ++r) {
            int row = (r & 3) + 8 * (r >> 2) + 4 * h;
            c0[r] = b_in[row];
            c1[r] = b_in[32 + row];
        }
        y0v = __builtin_amdgcn_mfma_f32_32x32x16_f16(a0, bx, c0, 0, 0, 0);
        y1v = __builtin_amdgcn_mfma_f32_32x32x16_f16(a1, bx, c1, 0, 0, 0);
    }

    // Build B-frags of tmp^T = (y + c*k)^T via wave-private LDS round-trip.
    // Write: lane (h,b) owns dims {32t+8g+4h+i}; read: B[k=16q+8h+j][n=b].
    auto build_frags = [&](float c, f32x16 k0, f32x16 k1, half8v* bb) {
        #pragma unroll
        for (int t = 0; t < 2; ++t) {
            const f32x16& yy = t ? y1v : y0v;
            const f32x16& kv = t ? k1 : k0;
            #pragma unroll
            for (int g = 0; g < 4; ++g) {
                float v0 = __builtin_fmaf(c, kv[4 * g + 0], yy[4 * g + 0]);
                float v1 = __builtin_fmaf(c, kv[4 * g + 1], yy[4 * g + 1]);
                float v2 = __builtin_fmaf(c, kv[4 * g + 2], yy[4 * g + 2]);
                float v3 = __builtin_fmaf(c, kv[4 * g + 3], yy[4 * g + 3]);
                half2v p0 = pack_f16(v0, v1);
                half2v p1 = pack_f16(v2, v3);
                half4v pk = __builtin_shufflevector(p0, p1, 0, 1, 2, 3);
                *(half4v*)(rowp + 32 * t + 8 * g + 4 * h) = pk;
            }
        }
        // wave-private scratch: in-order DS per wave + lgkmcnt(0) is sufficient
        __asm__ volatile("s_waitcnt lgkmcnt(0)" ::: "memory");
        #pragma unroll
        for (int q = 0; q < 4; ++q) {
            half4v lo = *(const half4v*)(rowp + 16 * q + 8 * h);
            half4v hi = *(const half4v*)(rowp + 16 * q + 8 * h + 4);
            bb[q] = __builtin_shufflevector(lo, hi, 0, 1, 2, 3, 4, 5, 6, 7);
        }
        // compiler fence: next iteration's DS writes must not hoist above these reads
        __asm__ volatile("" ::: "memory");
    };

    auto feval = [&](float c, f32x16 ki0, f32x16 ki1, f32x16& ko0, f32x16& ko1) {
        half8v bb[4];
        build_frags(c, ki0, ki1, bb);
        f32x16 s0 = bias0, s1 = bias1;
        #pragma unroll
        for (int q = 0; q < 4; ++q) {
            s0 = __builtin_amdgcn_mfma_f32_32x32x16_f16(a_wf0[q], bb[q], s0, 0, 0, 0);
            s1 = __builtin_amdgcn_mfma_f32_32x32x16_f16(a_wf1[q], bb[q], s1, 0, 0, 0);
        }
        #pragma unroll
        for (int r = 0; r < 16; ++r) {
            ko0[r] = fast_tanh(s0[r]);
            ko1[r] = fast_tanh(s1[r]);
        }
    };

    const float dt = 1.0f / N_STEPS;

    #pragma unroll 1
    for (int s = 0; s < N_STEPS; ++s) {
        f32x16 k0, k1, yn0, yn1;

        feval(0.0f, y0v, y1v, k0, k1);                       // k1
        #pragma unroll
        for (int r = 0; r < 16; ++r) {
            yn0[r] = __builtin_fmaf(dt / 6.0f, k0[r], y0v[r]);
            yn1[r] = __builtin_fmaf(dt / 6.0f, k1[r], y1v[r]);
        }
        feval(0.5f * dt, k0, k1, k0, k1);                    // k2
        #pragma unroll
        for (int r = 0; r < 16; ++r) {
            yn0[r] = __builtin_fmaf(dt / 3.0f, k0[r], yn0[r]);
            yn1[r] = __builtin_fmaf(dt / 3.0f, k1[r], yn1[r]);
        }
        feval(0.5f * dt, k0, k1, k0, k1);                    // k3
        #pragma unroll
        for (int r = 0; r < 16; ++r) {
            yn0[r] = __builtin_fmaf(dt / 3.0f, k0[r], yn0[r]);
            yn1[r] = __builtin_fmaf(dt / 3.0f, k1[r], yn1[r]);
        }
        feval(dt, k0, k1, k0, k1);                           // k4
        #pragma unroll
        for (int r = 0; r < 16; ++r) {
            y0v[r] = __builtin_fmaf(dt / 6.0f, k0[r], yn0[r]);
            y1v[r] = __builtin_fmaf(dt / 6.0f, k1[r], yn1[r]);
        }
    }

    // ---- readout: out^T = W_out^T @ y1^T + b_out (M-tile of 32, rows >=16 garbage) ----
    {
        half8v bb[4];
        build_frags(0.0f, y0v, y1v, bb);
        half8v a_wo[4];
        #pragma unroll
        for (int q = 0; q < 4; ++q) {
            #pragma unroll
            for (int j = 0; j < 8; ++j) {
                int k = 16 * q + 8 * h + j;
                a_wo[q][j] = (b < OUT_DIM) ? (_Float16)W_out[k * OUT_DIM + b]
                                           : (_Float16)0.0f;
            }
        }
        f32x16 so;
        #pragma unroll
        for (int r = 0; r < 16; ++r) {
            int o = (r & 3) + 8 * (r >> 2) + 4 * h;
            so[r] = (r < 8) ? b_out[o] : 0.0f;
        }
        #pragma unroll
        for (int q = 0; q < 4; ++q)
            so = __builtin_amdgcn_mfma_f32_32x32x16_f16(a_wo[q], bb[q], so, 0, 0, 0);

        // lane (h,b): regs 0-3 -> out dims 4h+0..3, regs 4-7 -> 8+4h+0..3
        float* op = out + (batch0 + b) * OUT_DIM;
        float4 o0 = make_float4(so[0], so[1], so[2], so[3]);
        float4 o1 = make_float4(so[4], so[5], so[6], so[7]);
        *(float4*)(op + 4 * h)     = o0;
        *(float4*)(op + 8 + 4 * h) = o1;
    }
}

extern "C" void kernel_launch(void* const* d_in, const int* in_sizes, int n_in,
                              void* d_out, int out_size, void* d_ws, size_t ws_size,
                              hipStream_t stream) {
    const float* x     = (const float*)d_in[0];
    const float* W_in  = (const float*)d_in[1];
    const float* b_in  = (const float*)d_in[2];
    const float* Wf    = (const float*)d_in[3];
    const float* bf    = (const float*)d_in[4];
    const float* W_out = (const float*)d_in[5];
    const float* b_out = (const float*)d_in[6];
    float* outp        = (float*)d_out;

    dim3 grid(BATCH / 128);   // 4 waves/block, 32 batch rows per wave
    dim3 block(256);
    hipLaunchKernelGGL(ode_rk4_kernel, grid, block, 0, stream,
                       x, W_in, b_in, Wf, bf, W_out, b_out, outp);
}